// Round 1
// baseline (367.148 us; speedup 1.0000x reference)
//
#include <hip/hip_runtime.h>

#define T_STEPS 512
#define HSTRIDE 72              // shorts per LDS h-row (16B-aligned, conflict-free)

typedef short short8 __attribute__((ext_vector_type(8)));
typedef float f32x4 __attribute__((ext_vector_type(4)));

__device__ __forceinline__ float ex2(float x) {
#if __has_builtin(__builtin_amdgcn_exp2f)
    return __builtin_amdgcn_exp2f(x);
#else
    return exp2f(x);
#endif
}
__device__ __forceinline__ float rcp_fast(float x) {
#if __has_builtin(__builtin_amdgcn_rcpf)
    return __builtin_amdgcn_rcpf(x);
#else
    return 1.0f / x;
#endif
}
__device__ __forceinline__ float fast_sig(float x) {
    return rcp_fast(1.0f + ex2(x * -1.442695041f));
}
__device__ __forceinline__ float fast_tanh(float x) {
    // tanh(x) = 1 - 2/(1+exp2(2x*log2e)); saturates correctly at +/-inf
    return fmaf(-2.0f, rcp_fast(1.0f + ex2(x * 2.885390082f)), 1.0f);
}
__device__ __forceinline__ unsigned short f2bf(float f) {
    union { float f; unsigned u; } v; v.f = f;
    unsigned r = v.u + 0x7fffu + ((v.u >> 16) & 1u);   // RNE
    return (unsigned short)(r >> 16);
}
__device__ __forceinline__ float bf2f(unsigned short b) {
    union { float f; unsigned u; } v; v.u = ((unsigned)b) << 16;
    return v.f;
}

// partial fc-dot over this lane's A-fragment slice, reduced over the 4 k-quads
__device__ __forceinline__ float out_dot(short8 a0, short8 a1,
                                         const float* wfc0, const float* wfc1) {
    float s = 0.f;
#pragma unroll
    for (int j = 0; j < 8; ++j) s = fmaf(bf2f((unsigned short)a0[j]), wfc0[j], s);
#pragma unroll
    for (int j = 0; j < 8; ++j) s = fmaf(bf2f((unsigned short)a1[j]), wfc1[j], s);
    s += __shfl_xor(s, 16);
    s += __shfl_xor(s, 32);
    return s;   // full 64-dot for batch row m = lane&15, on all lanes
}

__global__ __launch_bounds__(256, 1) void lstm_kernel(
    const float* __restrict__ x, const float* __restrict__ w_ih,
    const float* __restrict__ w_hh, const float* __restrict__ b_ih,
    const float* __restrict__ b_hh, const float* __restrict__ w_fc,
    const float* __restrict__ b_fc, float* __restrict__ out)
{
    __shared__ __align__(16) unsigned short hbuf[2][16 * HSTRIDE];

    const int tid  = threadIdx.x;
    const int w    = tid >> 6;      // wave 0..3 -> owns hidden units 16w..16w+15
    const int lane = tid & 63;
    const int qq   = lane >> 4;     // k-quad / row-group
    const int c    = lane & 15;     // N-col (gate/unit) and A-row (batch)
    const int b0   = blockIdx.x * 16;

    // zero read-buffer for step 0 (h_{-1} = 0)
    for (int i = tid; i < 16 * HSTRIDE; i += 256) hbuf[0][i] = 0;

    // ---- B fragments (weights) in VGPRs: tile n = gate class, K-frag kk ----
    // B[k][ncol]: lane holds k = 32*kk + 8*qq + j, ncol = c; gate g = 64n+16w+c
    short8 bfrag[4][2];
    float bias_n[4], wih_n[4];
#pragma unroll
    for (int n = 0; n < 4; ++n) {
        int g = 64 * n + 16 * w + c;
        bias_n[n] = b_ih[g] + b_hh[g];
        wih_n[n]  = w_ih[g];
#pragma unroll
        for (int kk = 0; kk < 2; ++kk) {
            const float* wp = w_hh + g * 64 + 32 * kk + 8 * qq;
            float4 lo = *(const float4*)(wp);
            float4 hi = *(const float4*)(wp + 4);
            short8 f;
            f[0] = (short)f2bf(lo.x); f[1] = (short)f2bf(lo.y);
            f[2] = (short)f2bf(lo.z); f[3] = (short)f2bf(lo.w);
            f[4] = (short)f2bf(hi.x); f[5] = (short)f2bf(hi.y);
            f[6] = (short)f2bf(hi.z); f[7] = (short)f2bf(hi.w);
            bfrag[n][kk] = f;
        }
    }

    // fc weights aligned to this lane's A-fragment k-slice
    float wfc0[8], wfc1[8];
#pragma unroll
    for (int j = 0; j < 8; ++j) { wfc0[j] = w_fc[8 * qq + j]; wfc1[j] = w_fc[32 + 8 * qq + j]; }
    const float bfc = b_fc[0];

    float cs[4] = {0.f, 0.f, 0.f, 0.f};   // fp32 cell state, rows qq*4+r

    const float* xrow[4];
#pragma unroll
    for (int r = 0; r < 4; ++r) xrow[r] = x + (size_t)(b0 + qq * 4 + r) * T_STEPS;

    // x double-buffer: 4 timesteps per quad
    float xcur[16], xnxt[16];
#pragma unroll
    for (int r = 0; r < 4; ++r) {
        float4 v = *(const float4*)(xrow[r]);
        xcur[4*r] = v.x; xcur[4*r+1] = v.y; xcur[4*r+2] = v.z; xcur[4*r+3] = v.w;
    }
#pragma unroll
    for (int r = 0; r < 4; ++r) {
        float4 v = *(const float4*)(xrow[r] + 4);
        xnxt[4*r] = v.x; xnxt[4*r+1] = v.y; xnxt[4*r+2] = v.z; xnxt[4*r+3] = v.w;
    }

    __syncthreads();

    short8 sa0 = {}, sa1 = {};     // saved A-frags for rotated fc-dot

    for (int tq = 0; tq < 128; ++tq) {
#pragma unroll
        for (int dt = 0; dt < 4; ++dt) {
            const int t  = tq * 4 + dt;
            const int rb = t & 1;
            const unsigned short* hrd = hbuf[rb];

            // A-frags: A[m=c][k=32kk+8qq+j] of h_{t-1}
            short8 a0 = *(const short8*)(hrd + c * HSTRIDE + 8 * qq);
            short8 a1 = *(const short8*)(hrd + c * HSTRIDE + 32 + 8 * qq);

            if (dt == w) { sa0 = a0; sa1 = a1; }   // rotate fc-dot ownership

            // acc init = x*w_ih + (b_ih+b_hh); C/D row = qq*4+r, col = c
            f32x4 acc[4];
#pragma unroll
            for (int n = 0; n < 4; ++n) {
                f32x4 a;
                a[0] = fmaf(xcur[0 * 4 + dt], wih_n[n], bias_n[n]);
                a[1] = fmaf(xcur[1 * 4 + dt], wih_n[n], bias_n[n]);
                a[2] = fmaf(xcur[2 * 4 + dt], wih_n[n], bias_n[n]);
                a[3] = fmaf(xcur[3 * 4 + dt], wih_n[n], bias_n[n]);
                acc[n] = __builtin_amdgcn_mfma_f32_16x16x32_bf16(a0, bfrag[n][0], a, 0, 0, 0);
                acc[n] = __builtin_amdgcn_mfma_f32_16x16x32_bf16(a1, bfrag[n][1], acc[n], 0, 0, 0);
            }

            // activations + state update; this wave owns units u = 16w+c
            unsigned short* hwr = hbuf[rb ^ 1];
#pragma unroll
            for (int r = 0; r < 4; ++r) {
                float gi = fast_sig(acc[0][r]);
                float gf = fast_sig(acc[1][r]);
                float gg = fast_tanh(acc[2][r]);
                float go = fast_sig(acc[3][r]);
                cs[r] = fmaf(gf, cs[r], gi * gg);
                float h = go * fast_tanh(cs[r]);
                hwr[(qq * 4 + r) * HSTRIDE + 16 * w + c] = f2bf(h);
            }
            __syncthreads();
        }

        // rotated fc-dot: this wave's saved frag is h_{tq*4+w-1} -> out[.][tq*4+w-1]
        {
            int st = tq * 4 + w;
            if (st > 0) {
                float s = out_dot(sa0, sa1, wfc0, wfc1);
                if (lane < 16) out[(size_t)(b0 + c) * T_STEPS + (st - 1)] = s + bfc;
            }
        }

        // rotate x buffers, prefetch quad tq+2
#pragma unroll
        for (int i = 0; i < 16; ++i) xcur[i] = xnxt[i];
        if (tq < 126) {
            const int t4n = (tq + 2) * 4;
#pragma unroll
            for (int r = 0; r < 4; ++r) {
                float4 v = *(const float4*)(xrow[r] + t4n);
                xnxt[4*r] = v.x; xnxt[4*r+1] = v.y; xnxt[4*r+2] = v.z; xnxt[4*r+3] = v.w;
            }
        }
    }

    // final output column: h_511 lives in hbuf[0] (step 511 wrote rb^1 = 0)
    if (w == 3) {
        const unsigned short* hrd = hbuf[0];
        short8 a0 = *(const short8*)(hrd + c * HSTRIDE + 8 * qq);
        short8 a1 = *(const short8*)(hrd + c * HSTRIDE + 32 + 8 * qq);
        float s = out_dot(a0, a1, wfc0, wfc1);
        if (lane < 16) out[(size_t)(b0 + c) * T_STEPS + (T_STEPS - 1)] = s + bfc;
    }
}

extern "C" void kernel_launch(void* const* d_in, const int* in_sizes, int n_in,
                              void* d_out, int out_size, void* d_ws, size_t ws_size,
                              hipStream_t stream) {
    const float* x    = (const float*)d_in[0];
    const float* w_ih = (const float*)d_in[1];
    const float* w_hh = (const float*)d_in[2];
    const float* b_ih = (const float*)d_in[3];
    const float* b_hh = (const float*)d_in[4];
    const float* w_fc = (const float*)d_in[5];
    const float* b_fc = (const float*)d_in[6];
    float* out = (float*)d_out;
    hipLaunchKernelGGL(lstm_kernel, dim3(128), dim3(256), 0, stream,
                       x, w_ih, w_hh, b_ih, b_hh, w_fc, b_fc, out);
}